// Round 2
// baseline (337.545 us; speedup 1.0000x reference)
//
#include <hip/hip_runtime.h>
#include <math.h>

// Problem constants (fixed by setup_inputs)
#define BB 16
#define CC 96
#define HH 112
#define WW 112
#define HO 56
#define WO 56
#define LL (HO*WO)       // 3136
#define CO 192
#define CKD 384          // C*K
#define NPIX (BB*LL)     // 50176

#define TPX 28           // pixels per tile (row-aligned: 56 = 2*28)
#define CHK 8            // channels per chunk
#define NCHUNK 12        // 96/8
#define WROWS 6          // window rows iy-2..iy+3
#define WCOLS 64         // window cols ix0-4..ix0+59 (aligned)
#define APAD 40          // u16 row stride of smA planes (80B: 16B-aligned rows)

// ws layout (floats): ssum=+16 (192), ssqs=+208 (192)
#define WS_SSUM  16
#define WS_SSQS  208
// bf16-swizzled w_def planes at byte offset 4096 (each 73728 ushorts)
#define WS_B_OFF 4096
#define B_ELEMS  73728

typedef short bf16x8 __attribute__((ext_vector_type(8)));
typedef float f32x4  __attribute__((ext_vector_type(4)));

__device__ __forceinline__ void split8(const float4 a0, const float4 a1,
                                       bf16x8& hi, bf16x8& lo)
{
    float f[8] = {a0.x, a0.y, a0.z, a0.w, a1.x, a1.y, a1.z, a1.w};
    #pragma unroll
    for (int j = 0; j < 8; ++j) {
        unsigned bits = __float_as_uint(f[j]);
        float fh = __uint_as_float(bits & 0xFFFF0000u);
        float fl = f[j] - fh;
        hi[j] = (short)(bits >> 16);
        lo[j] = (short)(__float_as_uint(fl) >> 16);
    }
}

// -------- K0 (fallback only): zero the stats accumulators --------
__global__ void k_zero(float* __restrict__ ws) {
    int t = threadIdx.x;
    if (t < 384) ws[WS_SSUM + t] = 0.f;
}

// -------- K-prep: w_def fp32 -> frag-ordered bf16 hi/lo planes (+stats zero) ----
// idx = ((ntg*12 + ks)*64 + lane)*8 + j ; n = ntg*16 + (lane&15), k = ks*32 + (lane>>4)*8 + j
__global__ void k_prep(const float* __restrict__ w_def,
                       unsigned short* __restrict__ bhi,
                       unsigned short* __restrict__ blo,
                       float* __restrict__ ws)
{
    if (blockIdx.x == 0 && threadIdx.x < 384) ws[WS_SSUM + threadIdx.x] = 0.f;
    int t = blockIdx.x * 256 + threadIdx.x;
    if (t >= 12 * 12 * 64) return;
    int ln  = t & 63;
    int ks  = (t >> 6) % 12;
    int ntg = t / (64 * 12);
    int n  = ntg * 16 + (ln & 15);
    int k0 = ks * 32 + (ln >> 4) * 8;
    const float* wp = w_def + (size_t)n * CKD + k0;
    #pragma unroll
    for (int j = 0; j < 8; ++j) {
        float f = wp[j];
        unsigned bits = __float_as_uint(f);
        float fh = __uint_as_float(bits & 0xFFFF0000u);
        float fl = f - fh;
        bhi[t * 8 + j] = (unsigned short)(bits >> 16);
        blo[t * 8 + j] = (unsigned short)(__float_as_uint(fl) >> 16);
    }
}

// ---- K2: fused offset-conv + bilinear sample + MFMA GEMM + stats + y store ----
// One block = 28 output pixels of one output row (tile never straddles rows).
template<bool PREP>
__global__ __launch_bounds__(256, 4) void k_main(
    const float* __restrict__ x,      // [B][C][H][W]
    const float* __restrict__ w_off,  // [8][C][2][2]
    const float* __restrict__ b_off,  // [8]
    const float* __restrict__ w_def,  // [CO][C][4] fp32 (fallback B source)
    const unsigned short* __restrict__ bhi,
    const unsigned short* __restrict__ blo,
    float* __restrict__ yout,         // d_out fp32 [B][L][CO] (pre-BN y)
    float* __restrict__ ws)
{
    __shared__ float win[CHK * WROWS * WCOLS];      // 12288 B (conv pass uses first 896 floats)
    __shared__ unsigned short smAh[32 * APAD];      // 2560 B  bf16 hi plane, frag layout
    __shared__ unsigned short smAl[32 * APAD];      // 2560 B  bf16 lo plane
    __shared__ float soff[TPX * 8];                 // 896 B

    const int tid = threadIdx.x;
    const int b  = blockIdx.y;
    const int bx = blockIdx.x;        // 0..111
    const int oy  = bx >> 1;
    const int ox0 = (bx & 1) * TPX;
    const int iy  = oy * 2;
    const int ix0 = ox0 * 2;
    const int ln = tid & 63;
    const int w  = tid >> 6;

    // ================= Pass 1: offset conv (from LDS-staged 2x56 windows) ======
    float dacc = 0.f;
    const int cpix = tid >> 3;        // 0..31 (active < 28)
    const int coch = tid & 7;
    const int spair = tid / 14;       // staging: (c,r) pair, tid<224
    const int sq    = tid % 14;
    for (int ch = 0; ch < NCHUNK; ++ch) {
        __syncthreads();
        if (tid < 224) {
            int c = spair >> 1, r = spair & 1;
            const float* src = x + (((size_t)(b * CC + ch * CHK + c) * HH) + iy + r) * WW + ix0 + sq * 4;
            *(float4*)&win[(c * 2 + r) * 56 + sq * 4] = *(const float4*)src;
        }
        __syncthreads();
        if (tid < 224) {
            const float* wb = w_off + (size_t)coch * (CC * 4) + ch * CHK * 4;
            #pragma unroll
            for (int c = 0; c < CHK; ++c) {
                float2 t0 = *(const float2*)&win[(c * 2 + 0) * 56 + 2 * cpix];
                float2 t1 = *(const float2*)&win[(c * 2 + 1) * 56 + 2 * cpix];
                float4 a = *(const float4*)(wb + c * 4);
                dacc += t0.x * a.x + t0.y * a.y + t1.x * a.z + t1.y * a.w;
            }
        }
    }
    if (tid < 224) soff[cpix * 8 + coch] = dacc + b_off[coch];
    // zero smA pad rows 28..31 (cols 0..31) so pad pixels contribute 0 to y/stats
    if (tid < 128) {
        int rr = 28 + (tid >> 5), cc = tid & 31;
        smAh[rr * APAD + cc] = 0;
        smAl[rr * APAD + cc] = 0;
    }

    // ================= Pass 2: per-chunk stage -> sample -> MFMA ===============
    const int row0 = ln & 15;         // A row / B col within tile
    const int kg   = ln >> 4;         // k-group
    const int skk = tid & 31;         // sampler: local ck column
    const int sc  = skk >> 2;         // local channel
    const int sk  = skk & 3;          // kernel tap
    const int sky = sk >> 1, skx = sk & 1;
    const int wr0 = iy - 2, wc0 = ix0 - 4;

    f32x4 acc[2][3];
    #pragma unroll
    for (int mt = 0; mt < 2; ++mt)
        #pragma unroll
        for (int nt = 0; nt < 3; ++nt)
            acc[mt][nt] = (f32x4){0.f, 0.f, 0.f, 0.f};

    for (int ch = 0; ch < NCHUNK; ++ch) {
        __syncthreads();   // win free (also orders soff/pad-zero writes on iter 0)
        // ---- stage window: 8ch x 6rows x 64cols, 3 float4 per thread ----
        #pragma unroll
        for (int j = 0; j < 3; ++j) {
            int li = tid + 256 * j;
            int cg = li & 15, pr = li >> 4;
            int r = pr % 6, c = pr / 6;
            int gr = min(max(wr0 + r, 0), HH - 1);
            int gc0 = wc0 + cg * 4;
            const float* src = x + (((size_t)(b * CC + ch * CHK + c) * HH) + gr) * WW;
            float4 v;
            if (gc0 >= 0 && gc0 <= WW - 4) {
                v = *(const float4*)(src + gc0);
            } else {
                v.x = src[min(max(gc0 + 0, 0), WW - 1)];
                v.y = src[min(max(gc0 + 1, 0), WW - 1)];
                v.z = src[min(max(gc0 + 2, 0), WW - 1)];
                v.w = src[min(max(gc0 + 3, 0), WW - 1)];
            }
            *(float4*)&win[(c * WROWS + r) * WCOLS + cg * 4] = v;
        }
        __syncthreads();
        // ---- sample 28x32 values from LDS window, write split bf16 frags ----
        {
            const float* xc = x + ((size_t)(b * CC + ch * CHK + sc) * HH) * WW;  // fallback
            const float* wchan = &win[(sc * WROWS) * WCOLS];
            #pragma unroll
            for (int j = 0; j < 4; ++j) {
                if (j < 3 || tid < 128) {
                    int pix = (tid >> 5) + 8 * j;         // 0..27
                    float2 so = *(const float2*)&soff[pix * 8 + 2 * sk];
                    float fy = (float)(iy + sky) + so.x;
                    float fx = (float)(ix0 + 2 * pix + skx) + so.y;
                    float y0f = floorf(fy), x0f = floorf(fx);
                    int y0 = (int)y0f, x0 = (int)x0f;
                    float wy1 = fy - y0f, wx1 = fx - x0f;
                    float wy0 = 1.f - wy1, wx0 = 1.f - wx1;
                    int y1 = y0 + 1, x1 = x0 + 1;
                    bool vy0 = (y0 >= 0) && (y0 <= HH - 1);
                    bool vy1 = (y1 >= 0) && (y1 <= HH - 1);
                    bool vx0 = (x0 >= 0) && (x0 <= WW - 1);
                    bool vx1 = (x1 >= 0) && (x1 <= WW - 1);
                    int cy0 = min(max(y0, 0), HH - 1), cy1 = min(max(y1, 0), HH - 1);
                    int cx0 = min(max(x0, 0), WW - 1), cx1 = min(max(x1, 0), WW - 1);
                    float w00 = (vy0 && vx0) ? wy0 * wx0 : 0.f;
                    float w01 = (vy0 && vx1) ? wy0 * wx1 : 0.f;
                    float w10 = (vy1 && vx0) ? wy1 * wx0 : 0.f;
                    float w11 = (vy1 && vx1) ? wy1 * wx1 : 0.f;
                    int ry0 = cy0 - wr0, ry1 = cy1 - wr0;
                    int rx0 = cx0 - wc0, rx1 = cx1 - wc0;
                    bool inw = ((unsigned)ry0 <= (unsigned)(WROWS - 1)) &&
                               ((unsigned)ry1 <= (unsigned)(WROWS - 1)) &&
                               ((unsigned)rx0 <= (unsigned)(WCOLS - 1)) &&
                               ((unsigned)rx1 <= (unsigned)(WCOLS - 1));
                    float v;
                    if (inw) {
                        v = w00 * wchan[ry0 * WCOLS + rx0] + w01 * wchan[ry0 * WCOLS + rx1]
                          + w10 * wchan[ry1 * WCOLS + rx0] + w11 * wchan[ry1 * WCOLS + rx1];
                    } else {
                        v = w00 * xc[cy0 * WW + cx0] + w01 * xc[cy0 * WW + cx1]
                          + w10 * xc[cy1 * WW + cx0] + w11 * xc[cy1 * WW + cx1];
                    }
                    unsigned u = __float_as_uint(v);
                    float fh = __uint_as_float(u & 0xFFFF0000u);
                    smAh[pix * APAD + skk] = (unsigned short)(u >> 16);
                    smAl[pix * APAD + skk] = (unsigned short)(__float_as_uint(v - fh) >> 16);
                }
            }
        }
        __syncthreads();
        // ---- MFMA: A frags from smA planes, B frags from prepped global ----
        bf16x8 ah[2], al[2];
        #pragma unroll
        for (int mt = 0; mt < 2; ++mt) {
            ah[mt] = *(const bf16x8*)&smAh[(mt * 16 + row0) * APAD + kg * 8];
            al[mt] = *(const bf16x8*)&smAl[(mt * 16 + row0) * APAD + kg * 8];
        }
        #pragma unroll
        for (int nt = 0; nt < 3; ++nt) {
            bf16x8 bh, bl;
            if (PREP) {
                size_t idx = ((size_t)(((w * 3 + nt) * 12 + ch) * 64) + ln) * 8;
                bh = *(const bf16x8*)(bhi + idx);
                bl = *(const bf16x8*)(blo + idx);
            } else {
                const float* wp = w_def + (size_t)(w * 48 + nt * 16 + row0) * CKD
                                + ch * 32 + kg * 8;
                float4 b0 = *(const float4*)wp;
                float4 b1 = *(const float4*)(wp + 4);
                split8(b0, b1, bh, bl);
            }
            #pragma unroll
            for (int mt = 0; mt < 2; ++mt) {
                acc[mt][nt] = __builtin_amdgcn_mfma_f32_16x16x32_bf16(ah[mt], bh, acc[mt][nt], 0, 0, 0);
                acc[mt][nt] = __builtin_amdgcn_mfma_f32_16x16x32_bf16(ah[mt], bl, acc[mt][nt], 0, 0, 0);
                acc[mt][nt] = __builtin_amdgcn_mfma_f32_16x16x32_bf16(al[mt], bh, acc[mt][nt], 0, 0, 0);
            }
        }
    }

    // ================= Phase C: stats + store straight from accumulators ========
    // C/D layout: col = lane&15 (=row0), row = kg*4 + reg (+16 per mt)
    #pragma unroll
    for (int nt = 0; nt < 3; ++nt) {
        float s = 0.f, q = 0.f;
        #pragma unroll
        for (int mt = 0; mt < 2; ++mt)
            #pragma unroll
            for (int r = 0; r < 4; ++r) {
                float v = acc[mt][nt][r];
                s += v; q += v * v;
            }
        s += __shfl_xor(s, 16); s += __shfl_xor(s, 32);
        q += __shfl_xor(q, 16); q += __shfl_xor(q, 32);
        if (ln < 16) {
            atomicAdd(&ws[WS_SSUM + w * 48 + nt * 16 + ln], s);
            atomicAdd(&ws[WS_SSQS + w * 48 + nt * 16 + ln], q);
        }
    }
    size_t obase = (size_t)b * LL + (size_t)oy * WO + ox0;
    #pragma unroll
    for (int mt = 0; mt < 2; ++mt)
        #pragma unroll
        for (int r = 0; r < 4; ++r) {
            int pp = mt * 16 + kg * 4 + r;
            if (pp < TPX) {
                float* dst = yout + (obase + pp) * CO + w * 48 + row0;
                dst[0]  = acc[mt][0][r];
                dst[16] = acc[mt][1][r];
                dst[32] = acc[mt][2][r];
            }
        }
}

// -------- K3: BN (per-block recompute of scale/shift) + exact GELU, in-place ----
__global__ __launch_bounds__(256) void k_bn_gelu(
    float* __restrict__ out,          // fp32, in/out, [B][L][CO]
    const float* __restrict__ gamma,
    const float* __restrict__ beta,
    const float* __restrict__ ws)
{
    __shared__ float ssc[CO], ssh[CO];
    int t = threadIdx.x;
    if (t < CO) {
        float n = (float)NPIX;
        float mu = ws[WS_SSUM + t] / n;
        float var = ws[WS_SSQS + t] / n - mu * mu;
        float sc = gamma[t] * rsqrtf(fmaxf(var, 0.f) + 1e-5f);
        ssc[t] = sc;
        ssh[t] = beta[t] - mu * sc;
    }
    __syncthreads();
    long long i4 = ((long long)blockIdx.x * 256 + t) * 4;
    if (i4 >= (long long)NPIX * CO) return;
    int o0 = (int)(i4 % CO);          // 4 | 192 -> quad stays in-channel-run
    float4* p = (float4*)(out + i4);
    float4 v = *p;
    float f[4] = { v.x, v.y, v.z, v.w };
    #pragma unroll
    for (int j = 0; j < 4; ++j) {
        float z = ssc[o0 + j] * f[j] + ssh[o0 + j];
        f[j] = 0.5f * z * (1.f + erff(z * 0.70710678118654752f));
    }
    v.x = f[0]; v.y = f[1]; v.z = f[2]; v.w = f[3];
    *p = v;
}

extern "C" void kernel_launch(void* const* d_in, const int* in_sizes, int n_in,
                              void* d_out, int out_size, void* d_ws, size_t ws_size,
                              hipStream_t stream)
{
    const float *x = nullptr, *w_off = nullptr, *b_off = nullptr;
    const float *w_def = nullptr, *gamma = nullptr, *beta = nullptr;
    for (int i = 0; i < n_in; ++i) {
        int s = in_sizes[i];
        if      (s == 19267584) x     = (const float*)d_in[i];
        else if (s == 3072)     w_off = (const float*)d_in[i];
        else if (s == 8)        b_off = (const float*)d_in[i];
        else if (s == 73728)    w_def = (const float*)d_in[i];
        else if (s == 192) { if (!gamma) gamma = (const float*)d_in[i];
                             else        beta  = (const float*)d_in[i]; }
    }
    if (!x || !w_off || !b_off || !w_def || !gamma || !beta) {
        x = (const float*)d_in[0]; w_off = (const float*)d_in[3];
        b_off = (const float*)d_in[4]; w_def = (const float*)d_in[5];
        gamma = (const float*)d_in[6]; beta = (const float*)d_in[7];
    }

    float* ws = (float*)d_ws;
    float* out = (float*)d_out;

    unsigned short* bhi = (unsigned short*)((char*)d_ws + WS_B_OFF);
    unsigned short* blo = bhi + B_ELEMS;
    bool prep = ws_size >= (size_t)(WS_B_OFF + 2 * B_ELEMS * sizeof(unsigned short));

    if (prep) {
        k_prep<<<36, 256, 0, stream>>>(w_def, bhi, blo, ws);
        k_main<true><<<dim3(112, BB), 256, 0, stream>>>(x, w_off, b_off, w_def, bhi, blo, out, ws);
    } else {
        k_zero<<<1, 384, 0, stream>>>(ws);
        k_main<false><<<dim3(112, BB), 256, 0, stream>>>(x, w_off, b_off, w_def, bhi, blo, out, ws);
    }
    k_bn_gelu<<<dim3((int)(((long long)NPIX*CO/4 + 255) / 256)), 256, 0, stream>>>(out, gamma, beta, ws);
}

// Round 3
// 308.160 us; speedup vs baseline: 1.0954x; 1.0954x over previous
//
#include <hip/hip_runtime.h>
#include <math.h>

// Problem constants (fixed by setup_inputs)
#define BB 16
#define CC 96
#define HH 112
#define WW 112
#define HO 56
#define WO 56
#define LL (HO*WO)       // 3136
#define CO 192
#define CKD 384          // C*K
#define NPIX (BB*LL)     // 50176

#define TPX 28           // pixels per tile (row-aligned: 56 = 2*28)
#define CHK 8            // channels per chunk
#define NCHUNK 12        // 96/8
#define WROWS 4          // window rows iy-1..iy+2 (halo +-1; fallback covers outliers)
#define WCOLS 64         // window cols ix0-4..ix0+59 (aligned)
#define WSTRIDE 260      // channel-plane stride in floats: 4*64+4 -> banks 0,4,..,28 per ch
#define APAD 40          // u16 row stride of smA planes (80B: 16B-aligned rows)

// ws layout (floats): ssum=+16 (192), ssqs=+208 (192)
#define WS_SSUM  16
#define WS_SSQS  208
// bf16-swizzled w_def planes at byte offset 4096 (each 73728 ushorts)
#define WS_B_OFF 4096
#define B_ELEMS  73728

typedef short bf16x8 __attribute__((ext_vector_type(8)));
typedef float f32x4  __attribute__((ext_vector_type(4)));

__device__ __forceinline__ void split8(const float4 a0, const float4 a1,
                                       bf16x8& hi, bf16x8& lo)
{
    float f[8] = {a0.x, a0.y, a0.z, a0.w, a1.x, a1.y, a1.z, a1.w};
    #pragma unroll
    for (int j = 0; j < 8; ++j) {
        unsigned bits = __float_as_uint(f[j]);
        float fh = __uint_as_float(bits & 0xFFFF0000u);
        float fl = f[j] - fh;
        hi[j] = (short)(bits >> 16);
        lo[j] = (short)(__float_as_uint(fl) >> 16);
    }
}

// -------- K0 (fallback only): zero the stats accumulators --------
__global__ void k_zero(float* __restrict__ ws) {
    int t = threadIdx.x;
    if (t < 384) ws[WS_SSUM + t] = 0.f;
}

// -------- K-prep: w_def fp32 -> frag-ordered bf16 hi/lo planes (+stats zero) ----
// idx = ((ntg*12 + ks)*64 + lane)*8 + j ; n = ntg*16 + (lane&15), k = ks*32 + (lane>>4)*8 + j
__global__ void k_prep(const float* __restrict__ w_def,
                       unsigned short* __restrict__ bhi,
                       unsigned short* __restrict__ blo,
                       float* __restrict__ ws)
{
    if (blockIdx.x == 0 && threadIdx.x < 384) ws[WS_SSUM + threadIdx.x] = 0.f;
    int t = blockIdx.x * 256 + threadIdx.x;
    if (t >= 12 * 12 * 64) return;
    int ln  = t & 63;
    int ks  = (t >> 6) % 12;
    int ntg = t / (64 * 12);
    int n  = ntg * 16 + (ln & 15);
    int k0 = ks * 32 + (ln >> 4) * 8;
    const float* wp = w_def + (size_t)n * CKD + k0;
    #pragma unroll
    for (int j = 0; j < 8; ++j) {
        float f = wp[j];
        unsigned bits = __float_as_uint(f);
        float fh = __uint_as_float(bits & 0xFFFF0000u);
        float fl = f - fh;
        bhi[t * 8 + j] = (unsigned short)(bits >> 16);
        blo[t * 8 + j] = (unsigned short)(__float_as_uint(fl) >> 16);
    }
}

// ---- K2: fused offset-conv + bilinear sample + MFMA GEMM + stats + y store ----
// One block = 28 output pixels of one output row (tile never straddles rows).
template<bool PREP>
__global__ __launch_bounds__(256, 4) void k_main(
    const float* __restrict__ x,      // [B][C][H][W]
    const float* __restrict__ w_off,  // [8][C][2][2]
    const float* __restrict__ b_off,  // [8]
    const float* __restrict__ w_def,  // [CO][C][4] fp32 (fallback B source)
    const unsigned short* __restrict__ bhi,
    const unsigned short* __restrict__ blo,
    float* __restrict__ yout,         // d_out fp32 [B][L][CO] (pre-BN y)
    float* __restrict__ ws)
{
    __shared__ float win[CHK * WSTRIDE];            // 8320 B (conv pass reuses first 896 floats)
    __shared__ unsigned short smAh[32 * APAD];      // 2560 B  bf16 hi plane, frag layout
    __shared__ unsigned short smAl[32 * APAD];      // 2560 B  bf16 lo plane
    __shared__ float soff[TPX * 8];                 // 896 B

    const int tid = threadIdx.x;
    const int b  = blockIdx.y;
    const int bx = blockIdx.x;        // 0..111
    const int oy  = bx >> 1;
    const int ox0 = (bx & 1) * TPX;
    const int iy  = oy * 2;
    const int ix0 = ox0 * 2;
    const int ln = tid & 63;
    const int w  = tid >> 6;

    // ================= Pass 1: offset conv (from LDS-staged 2x56 windows) ======
    float dacc = 0.f;
    const int cpix = tid >> 3;        // 0..31 (active < 28)
    const int coch = tid & 7;
    const int spair = tid / 14;       // staging: (c,r) pair, tid<224
    const int sq    = tid % 14;
    for (int ch = 0; ch < NCHUNK; ++ch) {
        __syncthreads();
        if (tid < 224) {
            int c = spair >> 1, r = spair & 1;
            const float* src = x + (((size_t)(b * CC + ch * CHK + c) * HH) + iy + r) * WW + ix0 + sq * 4;
            *(float4*)&win[(c * 2 + r) * 56 + sq * 4] = *(const float4*)src;
        }
        __syncthreads();
        if (tid < 224) {
            const float* wb = w_off + (size_t)coch * (CC * 4) + ch * CHK * 4;
            #pragma unroll
            for (int c = 0; c < CHK; ++c) {
                float2 t0 = *(const float2*)&win[(c * 2 + 0) * 56 + 2 * cpix];
                float2 t1 = *(const float2*)&win[(c * 2 + 1) * 56 + 2 * cpix];
                float4 a = *(const float4*)(wb + c * 4);
                dacc += t0.x * a.x + t0.y * a.y + t1.x * a.z + t1.y * a.w;
            }
        }
    }
    if (tid < 224) soff[cpix * 8 + coch] = dacc + b_off[coch];
    // zero smA pad rows 28..31 (cols 0..31) so pad pixels contribute 0 to y/stats
    if (tid < 128) {
        int rr = 28 + (tid >> 5), cc = tid & 31;
        smAh[rr * APAD + cc] = 0;
        smAl[rr * APAD + cc] = 0;
    }

    // ================= Pass 2: per-chunk stage -> sample -> MFMA ===============
    // Descending chunk order: start with the chunk pass-1 fetched last (L2-warm).
    const int row0 = ln & 15;         // A row / B col within tile
    const int kg   = ln >> 4;         // k-group
    const int skk = tid & 31;         // sampler: local ck column
    const int sc  = skk >> 2;         // local channel
    const int sk  = skk & 3;          // kernel tap
    const int sky = sk >> 1, skx = sk & 1;
    const int wr0 = iy - 1, wc0 = ix0 - 4;

    f32x4 acc[2][3];
    #pragma unroll
    for (int mt = 0; mt < 2; ++mt)
        #pragma unroll
        for (int nt = 0; nt < 3; ++nt)
            acc[mt][nt] = (f32x4){0.f, 0.f, 0.f, 0.f};

    for (int ch = NCHUNK - 1; ch >= 0; --ch) {
        __syncthreads();   // win free (also orders soff/pad-zero writes on first iter)
        // ---- stage window: 8ch x 4rows x 64cols, 2 float4 per thread ----
        #pragma unroll
        for (int j = 0; j < 2; ++j) {
            int li = tid + 256 * j;   // 0..511
            int cg = li & 15;
            int pr = li >> 4;         // 0..31
            int r = pr & 3, c = pr >> 2;
            int gr = min(max(wr0 + r, 0), HH - 1);
            int gc0 = wc0 + cg * 4;
            const float* src = x + (((size_t)(b * CC + ch * CHK + c) * HH) + gr) * WW;
            float4 v;
            if (gc0 >= 0 && gc0 <= WW - 4) {
                v = *(const float4*)(src + gc0);
            } else {
                v.x = src[min(max(gc0 + 0, 0), WW - 1)];
                v.y = src[min(max(gc0 + 1, 0), WW - 1)];
                v.z = src[min(max(gc0 + 2, 0), WW - 1)];
                v.w = src[min(max(gc0 + 3, 0), WW - 1)];
            }
            *(float4*)&win[c * WSTRIDE + r * WCOLS + cg * 4] = v;
        }
        __syncthreads();
        // ---- sample 28x32 values from LDS window, write split bf16 frags ----
        {
            const float* xc = x + ((size_t)(b * CC + ch * CHK + sc) * HH) * WW;  // fallback
            const float* wchan = &win[sc * WSTRIDE];
            #pragma unroll
            for (int j = 0; j < 4; ++j) {
                if (j < 3 || tid < 128) {
                    int pix = (tid >> 5) + 8 * j;         // 0..27
                    float2 so = *(const float2*)&soff[pix * 8 + 2 * sk];
                    float fy = (float)(iy + sky) + so.x;
                    float fx = (float)(ix0 + 2 * pix + skx) + so.y;
                    float y0f = floorf(fy), x0f = floorf(fx);
                    int y0 = (int)y0f, x0 = (int)x0f;
                    float wy1 = fy - y0f, wx1 = fx - x0f;
                    float wy0 = 1.f - wy1, wx0 = 1.f - wx1;
                    int y1 = y0 + 1, x1 = x0 + 1;
                    bool vy0 = (y0 >= 0) && (y0 <= HH - 1);
                    bool vy1 = (y1 >= 0) && (y1 <= HH - 1);
                    bool vx0 = (x0 >= 0) && (x0 <= WW - 1);
                    bool vx1 = (x1 >= 0) && (x1 <= WW - 1);
                    int cy0 = min(max(y0, 0), HH - 1), cy1 = min(max(y1, 0), HH - 1);
                    int cx0 = min(max(x0, 0), WW - 1), cx1 = min(max(x1, 0), WW - 1);
                    float w00 = (vy0 && vx0) ? wy0 * wx0 : 0.f;
                    float w01 = (vy0 && vx1) ? wy0 * wx1 : 0.f;
                    float w10 = (vy1 && vx0) ? wy1 * wx0 : 0.f;
                    float w11 = (vy1 && vx1) ? wy1 * wx1 : 0.f;
                    int ry0 = cy0 - wr0, ry1 = cy1 - wr0;
                    int rx0 = cx0 - wc0, rx1 = cx1 - wc0;
                    bool inw = ((unsigned)ry0 <= (unsigned)(WROWS - 1)) &&
                               ((unsigned)ry1 <= (unsigned)(WROWS - 1)) &&
                               ((unsigned)rx0 <= (unsigned)(WCOLS - 1)) &&
                               ((unsigned)rx1 <= (unsigned)(WCOLS - 1));
                    float v;
                    if (inw) {
                        v = w00 * wchan[ry0 * WCOLS + rx0] + w01 * wchan[ry0 * WCOLS + rx1]
                          + w10 * wchan[ry1 * WCOLS + rx0] + w11 * wchan[ry1 * WCOLS + rx1];
                    } else {
                        v = w00 * xc[cy0 * WW + cx0] + w01 * xc[cy0 * WW + cx1]
                          + w10 * xc[cy1 * WW + cx0] + w11 * xc[cy1 * WW + cx1];
                    }
                    unsigned u = __float_as_uint(v);
                    float fh = __uint_as_float(u & 0xFFFF0000u);
                    smAh[pix * APAD + skk] = (unsigned short)(u >> 16);
                    smAl[pix * APAD + skk] = (unsigned short)(__float_as_uint(v - fh) >> 16);
                }
            }
        }
        __syncthreads();
        // ---- MFMA: A frags from smA planes, B frags from prepped global ----
        bf16x8 ah[2], al[2];
        #pragma unroll
        for (int mt = 0; mt < 2; ++mt) {
            ah[mt] = *(const bf16x8*)&smAh[(mt * 16 + row0) * APAD + kg * 8];
            al[mt] = *(const bf16x8*)&smAl[(mt * 16 + row0) * APAD + kg * 8];
        }
        #pragma unroll
        for (int nt = 0; nt < 3; ++nt) {
            bf16x8 bh, bl;
            if (PREP) {
                size_t idx = ((size_t)(((w * 3 + nt) * 12 + ch) * 64) + ln) * 8;
                bh = *(const bf16x8*)(bhi + idx);
                bl = *(const bf16x8*)(blo + idx);
            } else {
                const float* wp = w_def + (size_t)(w * 48 + nt * 16 + row0) * CKD
                                + ch * 32 + kg * 8;
                float4 b0 = *(const float4*)wp;
                float4 b1 = *(const float4*)(wp + 4);
                split8(b0, b1, bh, bl);
            }
            #pragma unroll
            for (int mt = 0; mt < 2; ++mt) {
                acc[mt][nt] = __builtin_amdgcn_mfma_f32_16x16x32_bf16(ah[mt], bh, acc[mt][nt], 0, 0, 0);
                acc[mt][nt] = __builtin_amdgcn_mfma_f32_16x16x32_bf16(ah[mt], bl, acc[mt][nt], 0, 0, 0);
                acc[mt][nt] = __builtin_amdgcn_mfma_f32_16x16x32_bf16(al[mt], bh, acc[mt][nt], 0, 0, 0);
            }
        }
    }

    // ================= Phase C: stats + store straight from accumulators ========
    // C/D layout: col = lane&15 (=row0), row = kg*4 + reg (+16 per mt)
    #pragma unroll
    for (int nt = 0; nt < 3; ++nt) {
        float s = 0.f, q = 0.f;
        #pragma unroll
        for (int mt = 0; mt < 2; ++mt)
            #pragma unroll
            for (int r = 0; r < 4; ++r) {
                float v = acc[mt][nt][r];
                s += v; q += v * v;
            }
        s += __shfl_xor(s, 16); s += __shfl_xor(s, 32);
        q += __shfl_xor(q, 16); q += __shfl_xor(q, 32);
        if (ln < 16) {
            atomicAdd(&ws[WS_SSUM + w * 48 + nt * 16 + ln], s);
            atomicAdd(&ws[WS_SSQS + w * 48 + nt * 16 + ln], q);
        }
    }
    size_t obase = (size_t)b * LL + (size_t)oy * WO + ox0;
    #pragma unroll
    for (int mt = 0; mt < 2; ++mt)
        #pragma unroll
        for (int r = 0; r < 4; ++r) {
            int pp = mt * 16 + kg * 4 + r;
            if (pp < TPX) {
                float* dst = yout + (obase + pp) * CO + w * 48 + row0;
                dst[0]  = acc[mt][0][r];
                dst[16] = acc[mt][1][r];
                dst[32] = acc[mt][2][r];
            }
        }
}

// -------- K3: BN (per-block recompute of scale/shift) + exact GELU, in-place ----
__global__ __launch_bounds__(256) void k_bn_gelu(
    float* __restrict__ out,          // fp32, in/out, [B][L][CO]
    const float* __restrict__ gamma,
    const float* __restrict__ beta,
    const float* __restrict__ ws)
{
    __shared__ float ssc[CO], ssh[CO];
    int t = threadIdx.x;
    if (t < CO) {
        float n = (float)NPIX;
        float mu = ws[WS_SSUM + t] / n;
        float var = ws[WS_SSQS + t] / n - mu * mu;
        float sc = gamma[t] * rsqrtf(fmaxf(var, 0.f) + 1e-5f);
        ssc[t] = sc;
        ssh[t] = beta[t] - mu * sc;
    }
    __syncthreads();
    long long i4 = ((long long)blockIdx.x * 256 + t) * 4;
    if (i4 >= (long long)NPIX * CO) return;
    int o0 = (int)(i4 % CO);          // 4 | 192 -> quad stays in-channel-run
    float4* p = (float4*)(out + i4);
    float4 v = *p;
    float f[4] = { v.x, v.y, v.z, v.w };
    #pragma unroll
    for (int j = 0; j < 4; ++j) {
        float z = ssc[o0 + j] * f[j] + ssh[o0 + j];
        f[j] = 0.5f * z * (1.f + erff(z * 0.70710678118654752f));
    }
    v.x = f[0]; v.y = f[1]; v.z = f[2]; v.w = f[3];
    *p = v;
}

extern "C" void kernel_launch(void* const* d_in, const int* in_sizes, int n_in,
                              void* d_out, int out_size, void* d_ws, size_t ws_size,
                              hipStream_t stream)
{
    const float *x = nullptr, *w_off = nullptr, *b_off = nullptr;
    const float *w_def = nullptr, *gamma = nullptr, *beta = nullptr;
    for (int i = 0; i < n_in; ++i) {
        int s = in_sizes[i];
        if      (s == 19267584) x     = (const float*)d_in[i];
        else if (s == 3072)     w_off = (const float*)d_in[i];
        else if (s == 8)        b_off = (const float*)d_in[i];
        else if (s == 73728)    w_def = (const float*)d_in[i];
        else if (s == 192) { if (!gamma) gamma = (const float*)d_in[i];
                             else        beta  = (const float*)d_in[i]; }
    }
    if (!x || !w_off || !b_off || !w_def || !gamma || !beta) {
        x = (const float*)d_in[0]; w_off = (const float*)d_in[3];
        b_off = (const float*)d_in[4]; w_def = (const float*)d_in[5];
        gamma = (const float*)d_in[6]; beta = (const float*)d_in[7];
    }

    float* ws = (float*)d_ws;
    float* out = (float*)d_out;

    unsigned short* bhi = (unsigned short*)((char*)d_ws + WS_B_OFF);
    unsigned short* blo = bhi + B_ELEMS;
    bool prep = ws_size >= (size_t)(WS_B_OFF + 2 * B_ELEMS * sizeof(unsigned short));

    if (prep) {
        k_prep<<<36, 256, 0, stream>>>(w_def, bhi, blo, ws);
        k_main<true><<<dim3(112, BB), 256, 0, stream>>>(x, w_off, b_off, w_def, bhi, blo, out, ws);
    } else {
        k_zero<<<1, 384, 0, stream>>>(ws);
        k_main<false><<<dim3(112, BB), 256, 0, stream>>>(x, w_off, b_off, w_def, bhi, blo, out, ws);
    }
    k_bn_gelu<<<dim3((int)(((long long)NPIX*CO/4 + 255) / 256)), 256, 0, stream>>>(out, gamma, beta, ws);
}